// Round 4
// baseline (1112.938 us; speedup 1.0000x reference)
//
#include <hip/hip_runtime.h>
#include <hip/hip_bf16.h>

#define BN_RSQ 0.9999950000374997f  // 1/sqrt(1+1e-5)

// ---------------------------------------------------------------------------
// Prefold BN into conv weights: wf = w*g*rsq, bf = b*g*rsq + a.
// ---------------------------------------------------------------------------
struct LayerP {
  const float* w; const float* b; const float* g; const float* a;
  float* wf; float* bf; int cout; int cin;
};
struct AllP { LayerP L[7]; };

__global__ void prefold_kernel(AllP A) {
  LayerP p = A.L[blockIdx.y];
  int n = p.cout * p.cin * 9;
  int i = blockIdx.x * 256 + threadIdx.x;
  if (i < n) {
    int o = i / (p.cin * 9);
    p.wf[i] = p.w[i] * p.g[o] * BN_RSQ;
  }
  if (i < p.cout) p.bf[i] = p.b[i] * p.g[i] * BN_RSQ + p.a[i];
}

// ---------------------------------------------------------------------------
// 3x3 SAME conv (+folded BN) + ReLU, 4-px-per-thread, software-pipelined.
//   Tile: 64x16 output px per block (256 threads = 16x16, thread = 4 x-px).
//   Pipeline per channel-chunk (CHUNK=4): ds_write(prefetch regs) ->
//   issue next chunk's global loads into regs -> ONE __syncthreads ->
//   compute. Global latency hides behind compute; 1 barrier/chunk.
//   - CIN1 ch from in1 (POOL_IN: 2x2 maxpool on the fly, in1 is [.,.,2H,2W]),
//     CIN2 ch from in2 (UP_IN2: bilinear 2x upsample align_corners=True,
//     in2 is [B,CIN2,H/2,W/2]).
//   - OSPLIT: output-channel split across blocks (blockIdx.z = og*8 + batch).
//   - FUSE_OUT: 1x1 conv + sigmoid epilogue (requires OSPLIT==1).
// All folded weights staged to LDS once at start (broadcast float4 reads).
// LDS tile stride 68: compute reads bank pattern (4tx+4ty)%32 = 2-way (free).
// ---------------------------------------------------------------------------
template <int CIN1, int CIN2, int COUTG, int OSPLIT, bool POOL_IN, bool UP_IN2,
          bool FUSE_OUT>
__launch_bounds__(256)
__global__ void conv3x3_cbr(const float* __restrict__ in1,
                            const float* __restrict__ in2,
                            const float* __restrict__ wf,
                            const float* __restrict__ bf,
                            const float* __restrict__ wout,
                            const float* __restrict__ bout,
                            float* __restrict__ out, int H, int W) {
  constexpr int CIN = CIN1 + CIN2;
  constexpr int COUT = COUTG * OSPLIT;
  constexpr int CHUNK = (CIN < 4) ? CIN : 4;
  constexpr int NC = CIN / CHUNK;
  constexpr int NBUF = (NC > 1) ? 2 : 1;
  constexpr int XT = 66;   // tile x extent (64 + 2 halo)
  constexpr int XS = 68;   // tile x stride
  constexpr int YT = 18;   // tile y extent (16 + 2 halo)
  constexpr int NSTAGE = CHUNK * YT * XT;
  constexpr int NPT = (NSTAGE + 255) / 256;

  __shared__ float tile[NBUF][CHUNK][YT][XS];
  __shared__ float wsm[COUTG * CIN * 12];

  const int tid = threadIdx.x;
  const int tx4 = (tid & 15) * 4;
  const int ty = tid >> 4;
  const int gx0 = blockIdx.x * 64;
  const int gy0 = blockIdx.y * 16;
  const int b = blockIdx.z & 7;
  const int og = blockIdx.z >> 3;
  const int obase = og * COUTG;

  // ---- stage ALL weights once ----
  for (int idx = tid; idx < COUTG * CIN * 9; idx += 256) {
    int o = idx / (CIN * 9);
    int r = idx - o * (CIN * 9);
    int c = r / 9;
    int t = r - c * 9;
    wsm[(o * CIN + c) * 12 + t] = wf[((obase + o) * CIN + c) * 9 + t];
  }

  float pre[NPT];

  // fetch one chunk's halo tile into registers
  auto stage = [&](int ci) {
#pragma unroll
    for (int k = 0; k < NPT; ++k) {
      int idx = tid + k * 256;
      if (idx < NSTAGE) {
        int c = idx / (YT * XT);
        int r = idx - c * (YT * XT);
        int yy = r / XT;
        int xx = r - yy * XT;
        int iy = gy0 + yy - 1;
        int ix = gx0 + xx - 1;
        int cg = ci * CHUNK + c;
        float v = 0.f;
        if (iy >= 0 && iy < H && ix >= 0 && ix < W) {
          if (CIN2 == 0 || cg < CIN1) {
            const int cb = b * CIN1 + cg;
            if (POOL_IN) {
              const float* p = in1 + (cb * (2 * H) + 2 * iy) * (2 * W) + 2 * ix;
              float v0 = p[0], v1 = p[1], v2 = p[2 * W], v3 = p[2 * W + 1];
              v = fmaxf(fmaxf(v0, v1), fmaxf(v2, v3));
            } else {
              v = in1[(cb * H + iy) * W + ix];
            }
          } else {
            const int cb = b * CIN2 + (cg - CIN1);
            if (UP_IN2) {
              const int Hi = H >> 1, Wi = W >> 1;
              const float sy = (float)(Hi - 1) / (float)(H - 1);
              const float sx = (float)(Wi - 1) / (float)(W - 1);
              float fy = iy * sy, fx = ix * sx;
              int y0 = (int)fy; int y1 = min(y0 + 1, Hi - 1);
              int x0 = (int)fx; int x1 = min(x0 + 1, Wi - 1);
              float wy = fy - (float)y0, wx = fx - (float)x0;
              const float* p = in2 + cb * Hi * Wi;
              float a00 = p[y0 * Wi + x0], a01 = p[y0 * Wi + x1];
              float a10 = p[y1 * Wi + x0], a11 = p[y1 * Wi + x1];
              float r0 = a00 * (1.f - wy) + a10 * wy;
              float r1 = a01 * (1.f - wy) + a11 * wy;
              v = r0 * (1.f - wx) + r1 * wx;
            } else {
              v = in2[(cb * H + iy) * W + ix];
            }
          }
        }
        pre[k] = v;
      }
    }
  };

  stage(0);

  float acc[COUTG][4];
#pragma unroll
  for (int o = 0; o < COUTG; ++o)
#pragma unroll
    for (int i = 0; i < 4; ++i) acc[o][i] = 0.f;

  for (int ci = 0; ci < NC; ++ci) {
    float* buf = &tile[ci % NBUF][0][0][0];
    // ---- write prefetched regs to LDS ----
#pragma unroll
    for (int k = 0; k < NPT; ++k) {
      int idx = tid + k * 256;
      if (idx < NSTAGE) {
        int c = idx / (YT * XT);
        int r = idx - c * (YT * XT);
        int yy = r / XT;
        int xx = r - yy * XT;
        buf[(c * YT + yy) * XS + xx] = pre[k];
      }
    }
    // ---- issue next chunk's global loads (latency hides behind compute) ----
    if (ci + 1 < NC) stage(ci + 1);
    __syncthreads();
    // ---- compute from LDS ----
#pragma unroll
    for (int c = 0; c < CHUNK; ++c) {
      float rr[3][6];
#pragma unroll
      for (int dy = 0; dy < 3; ++dy) {
        const float* p = &buf[(c * YT + ty + dy) * XS + tx4];
        float4 a4 = *(const float4*)p;
        float2 b2 = *(const float2*)(p + 4);
        rr[dy][0] = a4.x; rr[dy][1] = a4.y; rr[dy][2] = a4.z; rr[dy][3] = a4.w;
        rr[dy][4] = b2.x; rr[dy][5] = b2.y;
      }
      const int cabs = ci * CHUNK + c;
#pragma unroll
      for (int o = 0; o < COUTG; ++o) {
        const float4* wp = (const float4*)&wsm[(o * CIN + cabs) * 12];
        float4 wa = wp[0];
        float4 wb = wp[1];
        float w8 = wsm[(o * CIN + cabs) * 12 + 8];
#pragma unroll
        for (int i = 0; i < 4; ++i) {
          float s = acc[o][i];
          s = fmaf(rr[0][i + 0], wa.x, s);
          s = fmaf(rr[0][i + 1], wa.y, s);
          s = fmaf(rr[0][i + 2], wa.z, s);
          s = fmaf(rr[1][i + 0], wa.w, s);
          s = fmaf(rr[1][i + 1], wb.x, s);
          s = fmaf(rr[1][i + 2], wb.y, s);
          s = fmaf(rr[2][i + 0], wb.z, s);
          s = fmaf(rr[2][i + 1], wb.w, s);
          s = fmaf(rr[2][i + 2], w8, s);
          acc[o][i] = s;
        }
      }
    }
  }

  const int oy = gy0 + ty;
  const int ox = gx0 + tx4;
  if (FUSE_OUT) {
    float4 sv;
    float* s = (float*)&sv;
#pragma unroll
    for (int i = 0; i < 4; ++i) s[i] = bout[0];
#pragma unroll
    for (int o = 0; o < COUTG; ++o) {
      float bo = bf[obase + o], wo = wout[o];
#pragma unroll
      for (int i = 0; i < 4; ++i) {
        float rr2 = fmaxf(acc[o][i] + bo, 0.f);
        s[i] = fmaf(rr2, wo, s[i]);
      }
    }
#pragma unroll
    for (int i = 0; i < 4; ++i) s[i] = 1.f / (1.f + __expf(-s[i]));
    *(float4*)&out[(b * H + oy) * W + ox] = sv;
  } else {
#pragma unroll
    for (int o = 0; o < COUTG; ++o) {
      float bo = bf[obase + o];
      float4 rv;
      float* r = (float*)&rv;
#pragma unroll
      for (int i = 0; i < 4; ++i) r[i] = fmaxf(acc[o][i] + bo, 0.f);
      *(float4*)&out[((b * COUT + obase + o) * H + oy) * W + ox] = rv;
    }
  }
}

// ---------------------------------------------------------------------------
// FCAS on the 64x64 channel x4[0,1].
// ---------------------------------------------------------------------------
__global__ void fcas_count_kernel(const float* __restrict__ ch,
                                  const float* __restrict__ w,
                                  const float* __restrict__ bb,
                                  float* __restrict__ scratch) {
  const int H = 64, W = 64, N = H * W;
  __shared__ float vals[N];
  for (int i = threadIdx.x; i < N; i += blockDim.x) vals[i] = ch[i];
  __syncthreads();
  int idx = blockIdx.x * blockDim.x + threadIdx.x;
  if (idx >= N) return;
  float v = vals[idx];
  int p = 0, n = 0, e = 0;
  for (int k = 0; k < N; ++k) {
    float u = vals[k];
    p += (u > v);
    n += (u == v);
    e += (u < v);
  }
  float val = ((float)p * w[0] + bb[0] + (float)n * w[1] + bb[1] +
               (float)e * w[2] + bb[2]) / 3.0f;
  int i = idx >> 6, j = idx & 63;
  bool interior = (i >= 1) && (i <= H - 2) && (j >= 1) && (j <= W - 2);
  scratch[idx] = interior ? val : v;
}

__global__ void fcas_copy_kernel(const float* __restrict__ scratch,
                                 float* __restrict__ ch) {
  int i = blockIdx.x * 256 + threadIdx.x;
  if (i < 4096) ch[i] = scratch[i];
}

// ---------------------------------------------------------------------------
extern "C" void kernel_launch(void* const* d_in, const int* in_sizes, int n_in,
                              void* d_out, int out_size, void* d_ws, size_t ws_size,
                              hipStream_t stream) {
  const float* x      = (const float*)d_in[0];
  const float* w_inc  = (const float*)d_in[1];
  const float* b_inc  = (const float*)d_in[2];
  const float* g_inc  = (const float*)d_in[3];
  const float* a_inc  = (const float*)d_in[4];
  const float* w_d1   = (const float*)d_in[5];
  const float* b_d1   = (const float*)d_in[6];
  const float* g_d1   = (const float*)d_in[7];
  const float* a_d1   = (const float*)d_in[8];
  const float* w_d2   = (const float*)d_in[9];
  const float* b_d2   = (const float*)d_in[10];
  const float* g_d2   = (const float*)d_in[11];
  const float* a_d2   = (const float*)d_in[12];
  const float* w_d3   = (const float*)d_in[13];
  const float* b_d3   = (const float*)d_in[14];
  const float* g_d3   = (const float*)d_in[15];
  const float* a_d3   = (const float*)d_in[16];
  const float* w_u2   = (const float*)d_in[17];
  const float* b_u2   = (const float*)d_in[18];
  const float* g_u2   = (const float*)d_in[19];
  const float* a_u2   = (const float*)d_in[20];
  const float* w_u3   = (const float*)d_in[21];
  const float* b_u3   = (const float*)d_in[22];
  const float* g_u3   = (const float*)d_in[23];
  const float* a_u3   = (const float*)d_in[24];
  const float* w_u4   = (const float*)d_in[25];
  const float* b_u4   = (const float*)d_in[26];
  const float* g_u4   = (const float*)d_in[27];
  const float* a_u4   = (const float*)d_in[28];
  const float* w_out  = (const float*)d_in[29];
  const float* b_out  = (const float*)d_in[30];
  const float* fcas_w = (const float*)d_in[31];
  const float* fcas_b = (const float*)d_in[32];

  float* ws = (float*)d_ws;
  float* x1  = ws;                     // 16,777,216
  float* x2  = x1 + 16777216;          //  8,388,608
  float* x3  = x2 + 8388608;           //  4,194,304
  float* x4  = x3 + 4194304;           //  1,048,576
  float* uo2 = x4 + 1048576;           //  2,097,152
  float* uo3 = uo2 + 2097152;          //  4,194,304
  float* fs  = uo3 + 4194304;          //  4,096
  float* wfp = fs + 4096;
  float* wf_inc = wfp;                 // 216
  float* wf_d1  = wf_inc + 216;        // 1152
  float* wf_d2  = wf_d1 + 1152;        // 4608
  float* wf_d3  = wf_d2 + 4608;        // 9216
  float* wf_u2  = wf_d3 + 9216;        // 9216
  float* wf_u3  = wf_u2 + 9216;        // 2304
  float* wf_u4  = wf_u3 + 2304;        // 576
  float* bf_inc = wf_u4 + 576;         // 8
  float* bf_d1  = bf_inc + 8;          // 16
  float* bf_d2  = bf_d1 + 16;          // 32
  float* bf_d3  = bf_d2 + 32;          // 32
  float* bf_u2  = bf_d3 + 32;          // 16
  float* bf_u3  = bf_u2 + 16;          // 8
  float* bf_u4  = bf_u3 + 8;           // 4
  float* outp = (float*)d_out;

  AllP A;
  A.L[0] = {w_inc, b_inc, g_inc, a_inc, wf_inc, bf_inc, 8, 3};
  A.L[1] = {w_d1, b_d1, g_d1, a_d1, wf_d1, bf_d1, 16, 8};
  A.L[2] = {w_d2, b_d2, g_d2, a_d2, wf_d2, bf_d2, 32, 16};
  A.L[3] = {w_d3, b_d3, g_d3, a_d3, wf_d3, bf_d3, 32, 32};
  A.L[4] = {w_u2, b_u2, g_u2, a_u2, wf_u2, bf_u2, 16, 64};
  A.L[5] = {w_u3, b_u3, g_u3, a_u3, wf_u3, bf_u3, 8, 32};
  A.L[6] = {w_u4, b_u4, g_u4, a_u4, wf_u4, bf_u4, 4, 16};
  prefold_kernel<<<dim3(36, 7), dim3(256), 0, stream>>>(A);

  dim3 blk(256);

  // inc: 3->8 @512 (2048 blocks)
  conv3x3_cbr<3, 0, 8, 1, false, false, false><<<dim3(8, 32, 8), blk, 0, stream>>>(
      x, nullptr, wf_inc, bf_inc, nullptr, nullptr, x1, 512, 512);
  // d1: pool(x1) -> 8->16 @256 (OSPLIT=2, 1024 blocks)
  conv3x3_cbr<8, 0, 8, 2, true, false, false><<<dim3(4, 16, 16), blk, 0, stream>>>(
      x1, nullptr, wf_d1, bf_d1, nullptr, nullptr, x2, 256, 256);
  // d2: pool(x2) -> 16->32 @128 (OSPLIT=8, 1024 blocks)
  conv3x3_cbr<16, 0, 4, 8, true, false, false><<<dim3(2, 8, 64), blk, 0, stream>>>(
      x2, nullptr, wf_d2, bf_d2, nullptr, nullptr, x3, 128, 128);
  // d3: pool(x3) -> 32->32 @64 (OSPLIT=16, 512 blocks)
  conv3x3_cbr<32, 0, 2, 16, true, false, false><<<dim3(1, 4, 128), blk, 0, stream>>>(
      x3, nullptr, wf_d3, bf_d3, nullptr, nullptr, x4, 64, 64);
  // FCAS on x4[0,1]
  fcas_count_kernel<<<dim3(16), blk, 0, stream>>>(x4 + 4096, fcas_w, fcas_b, fs);
  fcas_copy_kernel<<<dim3(16), blk, 0, stream>>>(fs, x4 + 4096);
  // u2: cat(x3, up2(x4)) 64->16 @128 (OSPLIT=4, 512 blocks)
  conv3x3_cbr<32, 32, 4, 4, false, true, false><<<dim3(2, 8, 32), blk, 0, stream>>>(
      x3, x4, wf_u2, bf_u2, nullptr, nullptr, uo2, 128, 128);
  // u3: cat(x2, up2(u2out)) 32->8 @256 (OSPLIT=2, 1024 blocks)
  conv3x3_cbr<16, 16, 4, 2, false, true, false><<<dim3(4, 16, 16), blk, 0, stream>>>(
      x2, uo2, wf_u3, bf_u3, nullptr, nullptr, uo3, 256, 256);
  // u4: cat(x1, up2(u3out)) 16->4 @512, fused 1x1+sigmoid (2048 blocks)
  conv3x3_cbr<8, 8, 4, 1, false, true, true><<<dim3(8, 32, 8), blk, 0, stream>>>(
      x1, uo3, wf_u4, bf_u4, w_out, b_out, outp, 512, 512);
}

// Round 5
// 701.274 us; speedup vs baseline: 1.5870x; 1.5870x over previous
//
#include <hip/hip_runtime.h>
#include <hip/hip_bf16.h>

#define BN_RSQ 0.9999950000374997f  // 1/sqrt(1+1e-5)

// ---------------------------------------------------------------------------
// Prefold BN into conv weights: wf = w*g*rsq, bf = b*g*rsq + a.
// ---------------------------------------------------------------------------
struct LayerP {
  const float* w; const float* b; const float* g; const float* a;
  float* wf; float* bf; int cout; int cin;
};
struct AllP { LayerP L[7]; };

__global__ void prefold_kernel(AllP A) {
  LayerP p = A.L[blockIdx.y];
  int n = p.cout * p.cin * 9;
  int i = blockIdx.x * 256 + threadIdx.x;
  if (i < n) {
    int o = i / (p.cin * 9);
    p.wf[i] = p.w[i] * p.g[o] * BN_RSQ;
  }
  if (i < p.cout) p.bf[i] = p.b[i] * p.g[i] * BN_RSQ + p.a[i];
}

// ---------------------------------------------------------------------------
// 3x3 SAME conv (+folded BN) + ReLU.
//   Tile: TX x 16 output px per block (256 threads; thread = TX/16 x-px).
//   TX=64 for high-res layers, TX=32 for low-res layers (more blocks -> TLP;
//   latency hiding comes from >=4 blocks/CU, NOT register prefetch — round-4
//   register pipelining drove VGPR 52->248 and regressed).
//   - CIN1 ch from in1 (POOL_IN: 2x2 maxpool on the fly, in1 is [.,.,2H,2W]),
//     CIN2 ch from in2 (UP_IN2: bilinear 2x upsample align_corners=True,
//     in2 is [B,CIN2,H/2,W/2]).
//   - OSPLIT: output-channel split across blocks (blockIdx.z = og*8 + batch).
//   - FUSE_OUT: 1x1 conv + sigmoid epilogue (requires OSPLIT==1).
// All folded weights staged to LDS once (broadcast float4 reads, no scalar
// loads in inner loop). Tile stride TX+4: aligned vector reads, 2-way banks.
// ---------------------------------------------------------------------------
template <int CIN1, int CIN2, int COUTG, int OSPLIT, int TX, bool POOL_IN,
          bool UP_IN2, bool FUSE_OUT>
__launch_bounds__(256)
__global__ void conv3x3_cbr(const float* __restrict__ in1,
                            const float* __restrict__ in2,
                            const float* __restrict__ wf,
                            const float* __restrict__ bf,
                            const float* __restrict__ wout,
                            const float* __restrict__ bout,
                            float* __restrict__ out, int H, int W) {
  constexpr int CIN = CIN1 + CIN2;
  constexpr int COUT = COUTG * OSPLIT;
  constexpr int PPT = TX / 16;        // px per thread (2 or 4)
  constexpr int CHUNK = (CIN < 4) ? CIN : 4;
  constexpr int XT = TX + 2;          // tile x extent
  constexpr int XS = TX + 4;          // tile x stride
  constexpr int YT = 18;              // tile y extent

  __shared__ float tile[CHUNK][YT][XS];
  __shared__ float wsm[COUTG * CIN * 12];

  const int tid = threadIdx.x;
  const int txp = (tid & 15) * PPT;
  const int ty = tid >> 4;
  const int gx0 = blockIdx.x * TX;
  const int gy0 = blockIdx.y * 16;
  const int b = blockIdx.z & 7;
  const int og = blockIdx.z >> 3;
  const int obase = og * COUTG;

  // ---- stage ALL folded weights once ----
  for (int idx = tid; idx < COUTG * CIN * 9; idx += 256) {
    int o = idx / (CIN * 9);
    int r = idx - o * (CIN * 9);
    int c = r / 9;
    int t = r - c * 9;
    wsm[(o * CIN + c) * 12 + t] = wf[((obase + o) * CIN + c) * 9 + t];
  }

  float acc[COUTG][PPT];
#pragma unroll
  for (int o = 0; o < COUTG; ++o)
#pragma unroll
    for (int i = 0; i < PPT; ++i) acc[o][i] = 0.f;

  for (int cc = 0; cc < CIN; cc += CHUNK) {
    __syncthreads();
    // ---- stage input tile (halo XT x 18 per channel), global -> LDS ----
    for (int idx = tid; idx < CHUNK * YT * XT; idx += 256) {
      int c = idx / (YT * XT);
      int r = idx - c * (YT * XT);
      int yy = r / XT;
      int xx = r - yy * XT;
      int iy = gy0 + yy - 1;
      int ix = gx0 + xx - 1;
      int cg = cc + c;
      float v = 0.f;
      if (iy >= 0 && iy < H && ix >= 0 && ix < W) {
        if (CIN2 == 0 || cg < CIN1) {
          const int cb = b * CIN1 + cg;
          if (POOL_IN) {
            const float* p = in1 + (cb * (2 * H) + 2 * iy) * (2 * W) + 2 * ix;
            float v0 = p[0], v1 = p[1], v2 = p[2 * W], v3 = p[2 * W + 1];
            v = fmaxf(fmaxf(v0, v1), fmaxf(v2, v3));
          } else {
            v = in1[(cb * H + iy) * W + ix];
          }
        } else {
          const int cb = b * CIN2 + (cg - CIN1);
          if (UP_IN2) {
            const int Hi = H >> 1, Wi = W >> 1;
            const float sy = (float)(Hi - 1) / (float)(H - 1);
            const float sx = (float)(Wi - 1) / (float)(W - 1);
            float fy = iy * sy, fx = ix * sx;
            int y0 = (int)fy; int y1 = min(y0 + 1, Hi - 1);
            int x0 = (int)fx; int x1 = min(x0 + 1, Wi - 1);
            float wy = fy - (float)y0, wx = fx - (float)x0;
            const float* p = in2 + cb * Hi * Wi;
            float a00 = p[y0 * Wi + x0], a01 = p[y0 * Wi + x1];
            float a10 = p[y1 * Wi + x0], a11 = p[y1 * Wi + x1];
            float r0 = a00 * (1.f - wy) + a10 * wy;
            float r1 = a01 * (1.f - wy) + a11 * wy;
            v = r0 * (1.f - wx) + r1 * wx;
          } else {
            v = in2[(cb * H + iy) * W + ix];
          }
        }
      }
      tile[c][yy][xx] = v;
    }
    __syncthreads();
    // ---- compute from LDS: vector reads + FMAs ----
#pragma unroll
    for (int c = 0; c < CHUNK; ++c) {
      float rr[3][PPT + 2];
#pragma unroll
      for (int dy = 0; dy < 3; ++dy) {
        const float* p = &tile[c][ty + dy][txp];
        if (PPT == 4) {
          float4 a4 = *(const float4*)p;        // 16B aligned
          float2 b2 = *(const float2*)(p + 4);  // 8B aligned
          rr[dy][0] = a4.x; rr[dy][1] = a4.y; rr[dy][2] = a4.z; rr[dy][3] = a4.w;
          rr[dy][4] = b2.x; rr[dy][5] = b2.y;
        } else {
          float2 a2 = *(const float2*)p;        // 8B aligned
          float2 b2 = *(const float2*)(p + 2);
          rr[dy][0] = a2.x; rr[dy][1] = a2.y; rr[dy][2] = b2.x; rr[dy][3] = b2.y;
        }
      }
      const int cabs = cc + c;
#pragma unroll
      for (int o = 0; o < COUTG; ++o) {
        const float4* wp = (const float4*)&wsm[(o * CIN + cabs) * 12];
        float4 wa = wp[0];
        float4 wb = wp[1];
        float w8 = wsm[(o * CIN + cabs) * 12 + 8];
#pragma unroll
        for (int i = 0; i < PPT; ++i) {
          float s = acc[o][i];
          s = fmaf(rr[0][i + 0], wa.x, s);
          s = fmaf(rr[0][i + 1], wa.y, s);
          s = fmaf(rr[0][i + 2], wa.z, s);
          s = fmaf(rr[1][i + 0], wa.w, s);
          s = fmaf(rr[1][i + 1], wb.x, s);
          s = fmaf(rr[1][i + 2], wb.y, s);
          s = fmaf(rr[2][i + 0], wb.z, s);
          s = fmaf(rr[2][i + 1], wb.w, s);
          s = fmaf(rr[2][i + 2], w8, s);
          acc[o][i] = s;
        }
      }
    }
  }

  const int oy = gy0 + ty;
  const int ox = gx0 + txp;
  if (FUSE_OUT) {
    float sv[PPT];
#pragma unroll
    for (int i = 0; i < PPT; ++i) sv[i] = bout[0];
#pragma unroll
    for (int o = 0; o < COUTG; ++o) {
      float bo = bf[obase + o], wo = wout[o];
#pragma unroll
      for (int i = 0; i < PPT; ++i) {
        float rr2 = fmaxf(acc[o][i] + bo, 0.f);
        sv[i] = fmaf(rr2, wo, sv[i]);
      }
    }
#pragma unroll
    for (int i = 0; i < PPT; ++i) sv[i] = 1.f / (1.f + __expf(-sv[i]));
    if (PPT == 4) *(float4*)&out[(b * H + oy) * W + ox] = *(float4*)sv;
    else          *(float2*)&out[(b * H + oy) * W + ox] = *(float2*)sv;
  } else {
#pragma unroll
    for (int o = 0; o < COUTG; ++o) {
      float bo = bf[obase + o];
      float rv[PPT];
#pragma unroll
      for (int i = 0; i < PPT; ++i) rv[i] = fmaxf(acc[o][i] + bo, 0.f);
      float* dst = &out[((b * COUT + obase + o) * H + oy) * W + ox];
      if (PPT == 4) *(float4*)dst = *(float4*)rv;
      else          *(float2*)dst = *(float2*)rv;
    }
  }
}

// ---------------------------------------------------------------------------
// FCAS on the 64x64 channel x4[0,1].
// ---------------------------------------------------------------------------
__global__ void fcas_count_kernel(const float* __restrict__ ch,
                                  const float* __restrict__ w,
                                  const float* __restrict__ bb,
                                  float* __restrict__ scratch) {
  const int H = 64, W = 64, N = H * W;
  __shared__ float vals[N];
  for (int i = threadIdx.x; i < N; i += blockDim.x) vals[i] = ch[i];
  __syncthreads();
  int idx = blockIdx.x * blockDim.x + threadIdx.x;
  if (idx >= N) return;
  float v = vals[idx];
  int p = 0, n = 0, e = 0;
  for (int k = 0; k < N; ++k) {
    float u = vals[k];
    p += (u > v);
    n += (u == v);
    e += (u < v);
  }
  float val = ((float)p * w[0] + bb[0] + (float)n * w[1] + bb[1] +
               (float)e * w[2] + bb[2]) / 3.0f;
  int i = idx >> 6, j = idx & 63;
  bool interior = (i >= 1) && (i <= H - 2) && (j >= 1) && (j <= W - 2);
  scratch[idx] = interior ? val : v;
}

__global__ void fcas_copy_kernel(const float* __restrict__ scratch,
                                 float* __restrict__ ch) {
  int i = blockIdx.x * 256 + threadIdx.x;
  if (i < 4096) ch[i] = scratch[i];
}

// ---------------------------------------------------------------------------
extern "C" void kernel_launch(void* const* d_in, const int* in_sizes, int n_in,
                              void* d_out, int out_size, void* d_ws, size_t ws_size,
                              hipStream_t stream) {
  const float* x      = (const float*)d_in[0];
  const float* w_inc  = (const float*)d_in[1];
  const float* b_inc  = (const float*)d_in[2];
  const float* g_inc  = (const float*)d_in[3];
  const float* a_inc  = (const float*)d_in[4];
  const float* w_d1   = (const float*)d_in[5];
  const float* b_d1   = (const float*)d_in[6];
  const float* g_d1   = (const float*)d_in[7];
  const float* a_d1   = (const float*)d_in[8];
  const float* w_d2   = (const float*)d_in[9];
  const float* b_d2   = (const float*)d_in[10];
  const float* g_d2   = (const float*)d_in[11];
  const float* a_d2   = (const float*)d_in[12];
  const float* w_d3   = (const float*)d_in[13];
  const float* b_d3   = (const float*)d_in[14];
  const float* g_d3   = (const float*)d_in[15];
  const float* a_d3   = (const float*)d_in[16];
  const float* w_u2   = (const float*)d_in[17];
  const float* b_u2   = (const float*)d_in[18];
  const float* g_u2   = (const float*)d_in[19];
  const float* a_u2   = (const float*)d_in[20];
  const float* w_u3   = (const float*)d_in[21];
  const float* b_u3   = (const float*)d_in[22];
  const float* g_u3   = (const float*)d_in[23];
  const float* a_u3   = (const float*)d_in[24];
  const float* w_u4   = (const float*)d_in[25];
  const float* b_u4   = (const float*)d_in[26];
  const float* g_u4   = (const float*)d_in[27];
  const float* a_u4   = (const float*)d_in[28];
  const float* w_out  = (const float*)d_in[29];
  const float* b_out  = (const float*)d_in[30];
  const float* fcas_w = (const float*)d_in[31];
  const float* fcas_b = (const float*)d_in[32];

  float* ws = (float*)d_ws;
  float* x1  = ws;                     // 16,777,216
  float* x2  = x1 + 16777216;          //  8,388,608
  float* x3  = x2 + 8388608;           //  4,194,304
  float* x4  = x3 + 4194304;           //  1,048,576
  float* uo2 = x4 + 1048576;           //  2,097,152
  float* uo3 = uo2 + 2097152;          //  4,194,304
  float* fs  = uo3 + 4194304;          //  4,096
  float* wfp = fs + 4096;
  float* wf_inc = wfp;                 // 216
  float* wf_d1  = wf_inc + 216;        // 1152
  float* wf_d2  = wf_d1 + 1152;        // 4608
  float* wf_d3  = wf_d2 + 4608;        // 9216
  float* wf_u2  = wf_d3 + 9216;        // 9216
  float* wf_u3  = wf_u2 + 9216;        // 2304
  float* wf_u4  = wf_u3 + 2304;        // 576
  float* bf_inc = wf_u4 + 576;         // 8
  float* bf_d1  = bf_inc + 8;          // 16
  float* bf_d2  = bf_d1 + 16;          // 32
  float* bf_d3  = bf_d2 + 32;          // 32
  float* bf_u2  = bf_d3 + 32;          // 16
  float* bf_u3  = bf_u2 + 16;          // 8
  float* bf_u4  = bf_u3 + 8;           // 4
  float* outp = (float*)d_out;

  AllP A;
  A.L[0] = {w_inc, b_inc, g_inc, a_inc, wf_inc, bf_inc, 8, 3};
  A.L[1] = {w_d1, b_d1, g_d1, a_d1, wf_d1, bf_d1, 16, 8};
  A.L[2] = {w_d2, b_d2, g_d2, a_d2, wf_d2, bf_d2, 32, 16};
  A.L[3] = {w_d3, b_d3, g_d3, a_d3, wf_d3, bf_d3, 32, 32};
  A.L[4] = {w_u2, b_u2, g_u2, a_u2, wf_u2, bf_u2, 16, 64};
  A.L[5] = {w_u3, b_u3, g_u3, a_u3, wf_u3, bf_u3, 8, 32};
  A.L[6] = {w_u4, b_u4, g_u4, a_u4, wf_u4, bf_u4, 4, 16};
  prefold_kernel<<<dim3(36, 7), dim3(256), 0, stream>>>(A);

  dim3 blk(256);

  // inc: 3->8 @512, TX=64 (2048 blocks)
  conv3x3_cbr<3, 0, 8, 1, 64, false, false, false><<<dim3(8, 32, 8), blk, 0, stream>>>(
      x, nullptr, wf_inc, bf_inc, nullptr, nullptr, x1, 512, 512);
  // d1: pool(x1) -> 8->16 @256, TX=64, OSPLIT=2 (1024 blocks)
  conv3x3_cbr<8, 0, 8, 2, 64, true, false, false><<<dim3(4, 16, 16), blk, 0, stream>>>(
      x1, nullptr, wf_d1, bf_d1, nullptr, nullptr, x2, 256, 256);
  // d2: pool(x2) -> 16->32 @128, TX=32, OSPLIT=8 (2048 blocks)
  conv3x3_cbr<16, 0, 4, 8, 32, true, false, false><<<dim3(4, 8, 64), blk, 0, stream>>>(
      x2, nullptr, wf_d2, bf_d2, nullptr, nullptr, x3, 128, 128);
  // d3: pool(x3) -> 32->32 @64, TX=32, OSPLIT=16 (1024 blocks)
  conv3x3_cbr<32, 0, 2, 16, 32, true, false, false><<<dim3(2, 4, 128), blk, 0, stream>>>(
      x3, nullptr, wf_d3, bf_d3, nullptr, nullptr, x4, 64, 64);
  // FCAS on x4[0,1]
  fcas_count_kernel<<<dim3(16), blk, 0, stream>>>(x4 + 4096, fcas_w, fcas_b, fs);
  fcas_copy_kernel<<<dim3(16), blk, 0, stream>>>(fs, x4 + 4096);
  // u2: cat(x3, up2(x4)) 64->16 @128, TX=32, OSPLIT=4 (1024 blocks)
  conv3x3_cbr<32, 32, 4, 4, 32, false, true, false><<<dim3(4, 8, 32), blk, 0, stream>>>(
      x3, x4, wf_u2, bf_u2, nullptr, nullptr, uo2, 128, 128);
  // u3: cat(x2, up2(u2out)) 32->8 @256, TX=64, OSPLIT=2 (1024 blocks)
  conv3x3_cbr<16, 16, 4, 2, 64, false, true, false><<<dim3(4, 16, 16), blk, 0, stream>>>(
      x2, uo2, wf_u3, bf_u3, nullptr, nullptr, uo3, 256, 256);
  // u4: cat(x1, up2(u3out)) 16->4 @512, TX=64, fused 1x1+sigmoid (2048 blocks)
  conv3x3_cbr<8, 8, 4, 1, 64, false, true, true><<<dim3(8, 32, 8), blk, 0, stream>>>(
      x1, uo3, wf_u4, bf_u4, w_out, b_out, outp, 512, 512);
}

// Round 6
// 661.512 us; speedup vs baseline: 1.6824x; 1.0601x over previous
//
#include <hip/hip_runtime.h>
#include <hip/hip_bf16.h>

#define BN_RSQ 0.9999950000374997f  // 1/sqrt(1+1e-5)

// ---------------------------------------------------------------------------
// Prefold BN into conv weights: wf = w*g*rsq, bf = b*g*rsq + a.
// ---------------------------------------------------------------------------
struct LayerP {
  const float* w; const float* b; const float* g; const float* a;
  float* wf; float* bf; int cout; int cin;
};
struct AllP { LayerP L[7]; };

__global__ void prefold_kernel(AllP A) {
  LayerP p = A.L[blockIdx.y];
  int n = p.cout * p.cin * 9;
  int i = blockIdx.x * 256 + threadIdx.x;
  if (i < n) {
    int o = i / (p.cin * 9);
    p.wf[i] = p.w[i] * p.g[o] * BN_RSQ;
  }
  if (i < p.cout) p.bf[i] = p.b[i] * p.g[i] * BN_RSQ + p.a[i];
}

// ---------------------------------------------------------------------------
// 3x3 SAME conv (+folded BN) + ReLU.
//   Tile: TX x 16 output px per block (256 threads; thread = TX/16 x-px).
//   Staging is ROW-BASED: each wave covers whole tile rows (lane = x), so
//   row-level work (c, yy, iy, y-bounds, y-lerp params) amortizes 64x and
//   interior x needs NO bounds check (gx0+xl always valid). X-halo columns
//   (2 per row) staged by a separate tiny loop. Per-lane x-lerp/pool offsets
//   hoisted out of the chunk loop entirely.  [round-5: linear-idx staging was
//   ~82% of VALU issue; round-4: register prefetch pipeline hit VGPR 248 and
//   regressed — latency hiding comes from >=4 blocks/CU TLP.]
//   - CIN1 ch from in1 (POOL_IN: 2x2 maxpool on the fly, in1 is [.,.,2H,2W]),
//     CIN2 ch from in2 (UP_IN2: bilinear 2x upsample align_corners=True,
//     in2 is [B,CIN2,H/2,W/2]).
//   - OSPLIT: output-channel split across blocks (blockIdx.z = og*8 + batch).
//   - FUSE_OUT: 1x1 conv + sigmoid epilogue (requires OSPLIT==1).
// ---------------------------------------------------------------------------
template <int CIN1, int CIN2, int COUTG, int OSPLIT, int TX, bool POOL_IN,
          bool UP_IN2, bool FUSE_OUT>
__launch_bounds__(256)
__global__ void conv3x3_cbr(const float* __restrict__ in1,
                            const float* __restrict__ in2,
                            const float* __restrict__ wf,
                            const float* __restrict__ bf,
                            const float* __restrict__ wout,
                            const float* __restrict__ bout,
                            float* __restrict__ out, int H, int W) {
  constexpr int CIN = CIN1 + CIN2;
  constexpr int COUT = COUTG * OSPLIT;
  constexpr int PPT = TX / 16;        // px per thread (2 or 4)
  constexpr int CHUNK = (CIN < 4) ? CIN : 4;
  constexpr int XT = TX + 2;          // tile x extent
  constexpr int XS = TX + 4;          // tile x stride
  constexpr int YT = 18;              // tile y extent
  constexpr int ROWS = CHUNK * YT;    // rows per chunk
  constexpr int RPW = (TX == 64) ? 1 : 2;  // rows per wave-pass

  __shared__ float tile[CHUNK][YT][XS];
  __shared__ float wsm[COUTG * CIN * 12];

  const int tid = threadIdx.x;
  const int txp = (tid & 15) * PPT;
  const int ty = tid >> 4;
  const int gx0 = blockIdx.x * TX;
  const int gy0 = blockIdx.y * 16;
  const int b = blockIdx.z & 7;
  const int og = blockIdx.z >> 3;
  const int obase = og * COUTG;

  const int lane = tid & 63;
  const int wv = tid >> 6;                       // wave id 0..3
  const int sub = (TX == 64) ? 0 : (lane >> 5);  // row-within-pass
  const int xl = (TX == 64) ? lane : (lane & 31);  // 0..TX-1
  const int ixi = gx0 + xl;                      // interior global x (valid)

  // hoisted per-lane x-params for the upsample path
  int ux0 = 0, ux1 = 0;
  float uwx = 0.f;
  if (UP_IN2) {
    const int Wi = W >> 1;
    const float sx = (float)(Wi - 1) / (float)(W - 1);
    float fx = ixi * sx;
    ux0 = (int)fx;
    ux1 = min(ux0 + 1, Wi - 1);
    uwx = fx - (float)ux0;
  }

  // ---- stage ALL folded weights once ----
  for (int idx = tid; idx < COUTG * CIN * 9; idx += 256) {
    int o = idx / (CIN * 9);
    int r = idx - o * (CIN * 9);
    int c = r / 9;
    int t = r - c * 9;
    wsm[(o * CIN + c) * 12 + t] = wf[((obase + o) * CIN + c) * 9 + t];
  }

  float acc[COUTG][PPT];
#pragma unroll
  for (int o = 0; o < COUTG; ++o)
#pragma unroll
    for (int i = 0; i < PPT; ++i) acc[o][i] = 0.f;

  for (int cc = 0; cc < CIN; cc += CHUNK) {
    __syncthreads();
    // ---- interior staging: wave = rows, lane = x, no x-bounds ----
    for (int pr = wv; pr * RPW < ROWS; pr += 4) {
      const int row = pr * RPW + sub;
      const int c = row / YT;
      const int yy = row - c * YT;
      const int iy = gy0 + yy - 1;
      const int cg = cc + c;
      float v = 0.f;
      if (iy >= 0 && iy < H) {
        if (CIN2 == 0 || cg < CIN1) {
          const int cb = b * CIN1 + cg;
          if (POOL_IN) {
            const float* p = in1 + (size_t)(cb * 2 * H + 2 * iy) * (2 * W) + 2 * ixi;
            float2 t0 = *(const float2*)p;
            float2 t1 = *(const float2*)(p + 2 * W);
            v = fmaxf(fmaxf(t0.x, t0.y), fmaxf(t1.x, t1.y));
          } else {
            v = in1[(size_t)(cb * H + iy) * W + ixi];
          }
        } else {
          const int cb = b * CIN2 + (cg - CIN1);
          const int Hi = H >> 1, Wi = W >> 1;
          const float sy = (float)(Hi - 1) / (float)(H - 1);
          float fy = iy * sy;
          int y0 = (int)fy;
          int y1 = min(y0 + 1, Hi - 1);
          float wy = fy - (float)y0;
          const float* r0p = in2 + (size_t)(cb * Hi + y0) * Wi;
          const float* r1p = in2 + (size_t)(cb * Hi + y1) * Wi;
          float a00 = r0p[ux0], a01 = r0p[ux1];
          float a10 = r1p[ux0], a11 = r1p[ux1];
          float r0 = a00 * (1.f - wy) + a10 * wy;
          float r1 = a01 * (1.f - wy) + a11 * wy;
          v = r0 * (1.f - uwx) + r1 * uwx;
        }
      }
      tile[c][yy][1 + xl] = v;
    }
    // ---- x-halo columns (2 per row, <=144 elements) ----
    for (int idx = tid; idx < 2 * ROWS; idx += 256) {
      const int row = idx >> 1;
      const int side = idx & 1;
      const int c = row / YT;
      const int yy = row - c * YT;
      const int iy = gy0 + yy - 1;
      const int ix = side ? (gx0 + TX) : (gx0 - 1);
      const int cg = cc + c;
      float v = 0.f;
      if (iy >= 0 && iy < H && ix >= 0 && ix < W) {
        if (CIN2 == 0 || cg < CIN1) {
          const int cb = b * CIN1 + cg;
          if (POOL_IN) {
            const float* p = in1 + (size_t)(cb * 2 * H + 2 * iy) * (2 * W) + 2 * ix;
            v = fmaxf(fmaxf(p[0], p[1]), fmaxf(p[2 * W], p[2 * W + 1]));
          } else {
            v = in1[(size_t)(cb * H + iy) * W + ix];
          }
        } else {
          const int cb = b * CIN2 + (cg - CIN1);
          const int Hi = H >> 1, Wi = W >> 1;
          const float sy = (float)(Hi - 1) / (float)(H - 1);
          const float sx = (float)(Wi - 1) / (float)(W - 1);
          float fy = iy * sy, fx = ix * sx;
          int y0 = (int)fy; int y1 = min(y0 + 1, Hi - 1);
          int x0 = (int)fx; int x1 = min(x0 + 1, Wi - 1);
          float wy = fy - (float)y0, wx = fx - (float)x0;
          const float* p = in2 + (size_t)cb * Hi * Wi;
          float a00 = p[y0 * Wi + x0], a01 = p[y0 * Wi + x1];
          float a10 = p[y1 * Wi + x0], a11 = p[y1 * Wi + x1];
          float r0 = a00 * (1.f - wy) + a10 * wy;
          float r1 = a01 * (1.f - wy) + a11 * wy;
          v = r0 * (1.f - wx) + r1 * wx;
        }
      }
      tile[c][yy][side ? (TX + 1) : 0] = v;
    }
    __syncthreads();
    // ---- compute from LDS: vector reads + FMAs ----
#pragma unroll
    for (int c = 0; c < CHUNK; ++c) {
      float rr[3][PPT + 2];
#pragma unroll
      for (int dy = 0; dy < 3; ++dy) {
        const float* p = &tile[c][ty + dy][txp];
        if (PPT == 4) {
          float4 a4 = *(const float4*)p;        // 16B aligned
          float2 b2 = *(const float2*)(p + 4);  // 8B aligned
          rr[dy][0] = a4.x; rr[dy][1] = a4.y; rr[dy][2] = a4.z; rr[dy][3] = a4.w;
          rr[dy][4] = b2.x; rr[dy][5] = b2.y;
        } else {
          float2 a2 = *(const float2*)p;        // 8B aligned
          float2 b2 = *(const float2*)(p + 2);
          rr[dy][0] = a2.x; rr[dy][1] = a2.y; rr[dy][2] = b2.x; rr[dy][3] = b2.y;
        }
      }
      const int cabs = cc + c;
#pragma unroll
      for (int o = 0; o < COUTG; ++o) {
        const float4* wp = (const float4*)&wsm[(o * CIN + cabs) * 12];
        float4 wa = wp[0];
        float4 wb = wp[1];
        float w8 = wsm[(o * CIN + cabs) * 12 + 8];
#pragma unroll
        for (int i = 0; i < PPT; ++i) {
          float s = acc[o][i];
          s = fmaf(rr[0][i + 0], wa.x, s);
          s = fmaf(rr[0][i + 1], wa.y, s);
          s = fmaf(rr[0][i + 2], wa.z, s);
          s = fmaf(rr[1][i + 0], wa.w, s);
          s = fmaf(rr[1][i + 1], wb.x, s);
          s = fmaf(rr[1][i + 2], wb.y, s);
          s = fmaf(rr[2][i + 0], wb.z, s);
          s = fmaf(rr[2][i + 1], wb.w, s);
          s = fmaf(rr[2][i + 2], w8, s);
          acc[o][i] = s;
        }
      }
    }
  }

  const int oy = gy0 + ty;
  const int ox = gx0 + txp;
  if (FUSE_OUT) {
    float sv[PPT];
#pragma unroll
    for (int i = 0; i < PPT; ++i) sv[i] = bout[0];
#pragma unroll
    for (int o = 0; o < COUTG; ++o) {
      float bo = bf[obase + o], wo = wout[o];
#pragma unroll
      for (int i = 0; i < PPT; ++i) {
        float rr2 = fmaxf(acc[o][i] + bo, 0.f);
        sv[i] = fmaf(rr2, wo, sv[i]);
      }
    }
#pragma unroll
    for (int i = 0; i < PPT; ++i) sv[i] = 1.f / (1.f + __expf(-sv[i]));
    if (PPT == 4) *(float4*)&out[(b * H + oy) * W + ox] = *(float4*)sv;
    else          *(float2*)&out[(b * H + oy) * W + ox] = *(float2*)sv;
  } else {
#pragma unroll
    for (int o = 0; o < COUTG; ++o) {
      float bo = bf[obase + o];
      float rv[PPT];
#pragma unroll
      for (int i = 0; i < PPT; ++i) rv[i] = fmaxf(acc[o][i] + bo, 0.f);
      float* dst = &out[((b * COUT + obase + o) * H + oy) * W + ox];
      if (PPT == 4) *(float4*)dst = *(float4*)rv;
      else          *(float2*)dst = *(float2*)rv;
    }
  }
}

// ---------------------------------------------------------------------------
// FCAS on the 64x64 channel x4[0,1].
// ---------------------------------------------------------------------------
__global__ void fcas_count_kernel(const float* __restrict__ ch,
                                  const float* __restrict__ w,
                                  const float* __restrict__ bb,
                                  float* __restrict__ scratch) {
  const int H = 64, W = 64, N = H * W;
  __shared__ float vals[N];
  for (int i = threadIdx.x; i < N; i += blockDim.x) vals[i] = ch[i];
  __syncthreads();
  int idx = blockIdx.x * blockDim.x + threadIdx.x;
  if (idx >= N) return;
  float v = vals[idx];
  int p = 0, n = 0, e = 0;
  for (int k = 0; k < N; ++k) {
    float u = vals[k];
    p += (u > v);
    n += (u == v);
    e += (u < v);
  }
  float val = ((float)p * w[0] + bb[0] + (float)n * w[1] + bb[1] +
               (float)e * w[2] + bb[2]) / 3.0f;
  int i = idx >> 6, j = idx & 63;
  bool interior = (i >= 1) && (i <= H - 2) && (j >= 1) && (j <= W - 2);
  scratch[idx] = interior ? val : v;
}

__global__ void fcas_copy_kernel(const float* __restrict__ scratch,
                                 float* __restrict__ ch) {
  int i = blockIdx.x * 256 + threadIdx.x;
  if (i < 4096) ch[i] = scratch[i];
}

// ---------------------------------------------------------------------------
extern "C" void kernel_launch(void* const* d_in, const int* in_sizes, int n_in,
                              void* d_out, int out_size, void* d_ws, size_t ws_size,
                              hipStream_t stream) {
  const float* x      = (const float*)d_in[0];
  const float* w_inc  = (const float*)d_in[1];
  const float* b_inc  = (const float*)d_in[2];
  const float* g_inc  = (const float*)d_in[3];
  const float* a_inc  = (const float*)d_in[4];
  const float* w_d1   = (const float*)d_in[5];
  const float* b_d1   = (const float*)d_in[6];
  const float* g_d1   = (const float*)d_in[7];
  const float* a_d1   = (const float*)d_in[8];
  const float* w_d2   = (const float*)d_in[9];
  const float* b_d2   = (const float*)d_in[10];
  const float* g_d2   = (const float*)d_in[11];
  const float* a_d2   = (const float*)d_in[12];
  const float* w_d3   = (const float*)d_in[13];
  const float* b_d3   = (const float*)d_in[14];
  const float* g_d3   = (const float*)d_in[15];
  const float* a_d3   = (const float*)d_in[16];
  const float* w_u2   = (const float*)d_in[17];
  const float* b_u2   = (const float*)d_in[18];
  const float* g_u2   = (const float*)d_in[19];
  const float* a_u2   = (const float*)d_in[20];
  const float* w_u3   = (const float*)d_in[21];
  const float* b_u3   = (const float*)d_in[22];
  const float* g_u3   = (const float*)d_in[23];
  const float* a_u3   = (const float*)d_in[24];
  const float* w_u4   = (const float*)d_in[25];
  const float* b_u4   = (const float*)d_in[26];
  const float* g_u4   = (const float*)d_in[27];
  const float* a_u4   = (const float*)d_in[28];
  const float* w_out  = (const float*)d_in[29];
  const float* b_out  = (const float*)d_in[30];
  const float* fcas_w = (const float*)d_in[31];
  const float* fcas_b = (const float*)d_in[32];

  float* ws = (float*)d_ws;
  float* x1  = ws;                     // 16,777,216
  float* x2  = x1 + 16777216;          //  8,388,608
  float* x3  = x2 + 8388608;           //  4,194,304
  float* x4  = x3 + 4194304;           //  1,048,576
  float* uo2 = x4 + 1048576;           //  2,097,152
  float* uo3 = uo2 + 2097152;          //  4,194,304
  float* fs  = uo3 + 4194304;          //  4,096
  float* wfp = fs + 4096;
  float* wf_inc = wfp;                 // 216
  float* wf_d1  = wf_inc + 216;        // 1152
  float* wf_d2  = wf_d1 + 1152;        // 4608
  float* wf_d3  = wf_d2 + 4608;        // 9216
  float* wf_u2  = wf_d3 + 9216;        // 9216
  float* wf_u3  = wf_u2 + 9216;        // 2304
  float* wf_u4  = wf_u3 + 2304;        // 576
  float* bf_inc = wf_u4 + 576;         // 8
  float* bf_d1  = bf_inc + 8;          // 16
  float* bf_d2  = bf_d1 + 16;          // 32
  float* bf_d3  = bf_d2 + 32;          // 32
  float* bf_u2  = bf_d3 + 32;          // 16
  float* bf_u3  = bf_u2 + 16;          // 8
  float* bf_u4  = bf_u3 + 8;           // 4
  float* outp = (float*)d_out;

  AllP A;
  A.L[0] = {w_inc, b_inc, g_inc, a_inc, wf_inc, bf_inc, 8, 3};
  A.L[1] = {w_d1, b_d1, g_d1, a_d1, wf_d1, bf_d1, 16, 8};
  A.L[2] = {w_d2, b_d2, g_d2, a_d2, wf_d2, bf_d2, 32, 16};
  A.L[3] = {w_d3, b_d3, g_d3, a_d3, wf_d3, bf_d3, 32, 32};
  A.L[4] = {w_u2, b_u2, g_u2, a_u2, wf_u2, bf_u2, 16, 64};
  A.L[5] = {w_u3, b_u3, g_u3, a_u3, wf_u3, bf_u3, 8, 32};
  A.L[6] = {w_u4, b_u4, g_u4, a_u4, wf_u4, bf_u4, 4, 16};
  prefold_kernel<<<dim3(36, 7), dim3(256), 0, stream>>>(A);

  dim3 blk(256);

  // inc: 3->8 @512, TX=64 (2048 blocks)
  conv3x3_cbr<3, 0, 8, 1, 64, false, false, false><<<dim3(8, 32, 8), blk, 0, stream>>>(
      x, nullptr, wf_inc, bf_inc, nullptr, nullptr, x1, 512, 512);
  // d1: pool(x1) -> 8->16 @256, TX=64, OSPLIT=2 (1024 blocks)
  conv3x3_cbr<8, 0, 8, 2, 64, true, false, false><<<dim3(4, 16, 16), blk, 0, stream>>>(
      x1, nullptr, wf_d1, bf_d1, nullptr, nullptr, x2, 256, 256);
  // d2: pool(x2) -> 16->32 @128, TX=32, OSPLIT=8 (2048 blocks)
  conv3x3_cbr<16, 0, 4, 8, 32, true, false, false><<<dim3(4, 8, 64), blk, 0, stream>>>(
      x2, nullptr, wf_d2, bf_d2, nullptr, nullptr, x3, 128, 128);
  // d3: pool(x3) -> 32->32 @64, TX=32, OSPLIT=16 (1024 blocks)
  conv3x3_cbr<32, 0, 2, 16, 32, true, false, false><<<dim3(2, 4, 128), blk, 0, stream>>>(
      x3, nullptr, wf_d3, bf_d3, nullptr, nullptr, x4, 64, 64);
  // FCAS on x4[0,1]
  fcas_count_kernel<<<dim3(16), blk, 0, stream>>>(x4 + 4096, fcas_w, fcas_b, fs);
  fcas_copy_kernel<<<dim3(16), blk, 0, stream>>>(fs, x4 + 4096);
  // u2: cat(x3, up2(x4)) 64->16 @128, TX=32, OSPLIT=4 (1024 blocks)
  conv3x3_cbr<32, 32, 4, 4, 32, false, true, false><<<dim3(4, 8, 32), blk, 0, stream>>>(
      x3, x4, wf_u2, bf_u2, nullptr, nullptr, uo2, 128, 128);
  // u3: cat(x2, up2(u2out)) 32->8 @256, TX=64, OSPLIT=2 (1024 blocks)
  conv3x3_cbr<16, 16, 4, 2, 64, false, true, false><<<dim3(4, 16, 16), blk, 0, stream>>>(
      x2, uo2, wf_u3, bf_u3, nullptr, nullptr, uo3, 256, 256);
  // u4: cat(x1, up2(u3out)) 16->4 @512, TX=64, fused 1x1+sigmoid (2048 blocks)
  conv3x3_cbr<8, 8, 4, 1, 64, false, true, true><<<dim3(8, 32, 8), blk, 0, stream>>>(
      x1, uo3, wf_u4, bf_u4, w_out, b_out, outp, 512, 512);
}